// Round 1
// baseline (510.223 us; speedup 1.0000x reference)
//
#include <hip/hip_runtime.h>
#include <hip/hip_bf16.h>

#define DHW (16 * 16 * 30)   // 7680 voxels per channel
#define NWCOL 7680           // hw columns = 120 f * 64 c
#define KTOT 30720           // hw rows
#define KSPLIT 240
#define KCH (KTOT / KSPLIT)  // 128
// ln(1024)/39
#define LN1024_OVER_39 0.17773004629742187f

// ---------------------------------------------------------------------------
// K1: conv chain at strided voxels only. One block per (b, zi, yi); 15 w's.
// Writes fvecT[k][b], k = ((ch*8+zi)*8+yi)*15 + w   (torch flatten order)
// ---------------------------------------------------------------------------
__global__ __launch_bounds__(256) void k1_conv(
    const float* __restrict__ feat0,
    const float* __restrict__ cw1, const float* __restrict__ cb1,
    const float* __restrict__ cw2, const float* __restrict__ cb2,
    const float* __restrict__ cw3, const float* __restrict__ cb3,
    float* __restrict__ fvecT)
{
    const int yi = blockIdx.x;   // 0..7
    const int zi = blockIdx.y;   // 0..7
    const int b  = blockIdx.z;   // 0..7
    const int t  = threadIdx.x;  // 0..255

    __shared__ float sIn[256][16];
    __shared__ float sH1[128][16];
    __shared__ float sH2[64][16];

    // ---- load input voxels: feat0[b, c, 2zi, 2yi, 2w], w = 0..14 ----
    {
        const int w  = t & 15;
        const int cg = t >> 4;  // 0..15
        const float* base = feat0 + (size_t)b * 256 * DHW
                            + (2 * zi) * (16 * 30) + (2 * yi) * 30 + 2 * w;
        for (int c0 = 0; c0 < 256; c0 += 16) {
            const int c = c0 + cg;
            sIn[c][w] = (w < 15) ? base[(size_t)c * DHW] : 0.f;
        }
    }
    __syncthreads();

    // ---- conv1: 256 -> 128, relu.  thread: o = t&127, half = t>>7 ----
    {
        const int o = t & 127, half = t >> 7;
        const int w0 = half * 8;
        float acc[8];
        #pragma unroll
        for (int i = 0; i < 8; ++i) acc[i] = cb1[o];
        for (int c = 0; c < 256; ++c) {
            const float wv = cw1[c * 128 + o];
            #pragma unroll
            for (int i = 0; i < 8; ++i) acc[i] += sIn[c][w0 + i] * wv;
        }
        #pragma unroll
        for (int i = 0; i < 8; ++i) sH1[o][w0 + i] = fmaxf(acc[i], 0.f);
    }
    __syncthreads();

    // ---- conv2: 128 -> 64, relu.  thread: o = t&63, q = t>>6 (w quad) ----
    {
        const int o = t & 63, q = t >> 6;
        const int w0 = q * 4;
        float acc[4];
        #pragma unroll
        for (int i = 0; i < 4; ++i) acc[i] = cb2[o];
        for (int c = 0; c < 128; ++c) {
            const float wv = cw2[c * 64 + o];
            #pragma unroll
            for (int i = 0; i < 4; ++i) acc[i] += sH1[c][w0 + i] * wv;
        }
        #pragma unroll
        for (int i = 0; i < 4; ++i) sH2[o][w0 + i] = fmaxf(acc[i], 0.f);
    }
    __syncthreads();

    // ---- conv3: 64 -> 32, relu, scatter to fvecT.  o = t&31, q = t>>5 ----
    {
        const int o = t & 31, q = t >> 5;  // q = 0..7
        const int w0 = q * 2;
        float acc[2];
        #pragma unroll
        for (int i = 0; i < 2; ++i) acc[i] = cb3[o];
        for (int c = 0; c < 64; ++c) {
            const float wv = cw3[c * 32 + o];
            #pragma unroll
            for (int i = 0; i < 2; ++i) acc[i] += sH2[c][w0 + i] * wv;
        }
        #pragma unroll
        for (int i = 0; i < 2; ++i) {
            const int w = w0 + i;
            if (w < 15) {
                const int k = ((o * 8 + zi) * 8 + yi) * 15 + w;
                fvecT[(size_t)k * 8 + b] = fmaxf(acc[i], 0.f);
            }
        }
    }
}

// ---------------------------------------------------------------------------
// K2: stream hw once; per lane: 4 consecutive columns (one f, four c's),
// acc[b][e] over a k-chunk; fold z[b,f] and atomically reduce into z1acc.
// grid = (15 column groups of 512 cols, KSPLIT k-chunks), 128 threads.
// ---------------------------------------------------------------------------
__global__ __launch_bounds__(128) void k2_stream(
    const float* __restrict__ hw,
    const float* __restrict__ fvecT,
    const float* __restrict__ coord,
    float* __restrict__ z1acc)
{
    __shared__ float zpart[512];
    const int t = threadIdx.x;
    #pragma unroll
    for (int r = 0; r < 4; ++r) zpart[t * 4 + r] = 0.f;
    __syncthreads();

    const int lane = t & 63;
    const int jw = blockIdx.x * 512 + (t >> 6) * 256;  // wave's 256-col strip
    const int j0 = jw + 4 * lane;                      // this lane's 4 cols
    const int kbase = blockIdx.y * KCH;

    float acc[8][4] = {};
    const float* hp = hw + (size_t)kbase * NWCOL + j0;
    const float* fp = fvecT + (size_t)kbase * 8;  // wave-uniform -> s_load

    for (int kk = 0; kk < KCH; ++kk) {
        const float4 h = *(const float4*)hp;
        hp += NWCOL;
        float fv[8];
        #pragma unroll
        for (int b = 0; b < 8; ++b) fv[b] = fp[b];
        fp += 8;
        #pragma unroll
        for (int b = 0; b < 8; ++b) {
            acc[b][0] += fv[b] * h.x;
            acc[b][1] += fv[b] * h.y;
            acc[b][2] += fv[b] * h.z;
            acc[b][3] += fv[b] * h.w;
        }
    }

    // fold z[b, f] for this lane's f; accumulate into LDS z1 partial
    const int f = j0 >> 6;           // 0..119, constant over the 4 cols
    const int i3 = f / 40;           // coord dim
    const int q = f - i3 * 40;       // freq index
    const float freqv = __expf((float)q * LN1024_OVER_39);
    const int cb = 4 * (lane & 15);  // column (mod 64) of element e=0

    #pragma unroll
    for (int b = 0; b < 8; ++b) {
        const float zv = coord[b * 3 + i3] * freqv;
        #pragma unroll
        for (int e = 0; e < 4; ++e)
            atomicAdd(&zpart[b * 64 + cb + e], zv * acc[b][e]);
    }
    __syncthreads();

    #pragma unroll
    for (int r = 0; r < 4; ++r) {
        const int idx = t * 4 + r;
        atomicAdd(&z1acc[idx], zpart[idx]);
    }
}

// ---------------------------------------------------------------------------
// K3: hb-bias term + 3-layer MLP tail. One block, 512 threads = (b=8, c=64).
// ---------------------------------------------------------------------------
__global__ __launch_bounds__(512) void k3_tail(
    const float* __restrict__ z1acc, const float* __restrict__ coord,
    const float* __restrict__ hb,
    const float* __restrict__ w1, const float* __restrict__ b1,
    const float* __restrict__ w2, const float* __restrict__ b2,
    const float* __restrict__ wo, const float* __restrict__ bo,
    float* __restrict__ out)
{
    __shared__ float sz[8][64];
    __shared__ float s2[8][64];
    __shared__ float sfreq[40];
    __shared__ float sc[24];
    const int t = threadIdx.x;
    if (t < 40) sfreq[t] = __expf((float)t * LN1024_OVER_39);
    if (t < 24) sc[t] = coord[t];
    __syncthreads();

    const int b = t >> 6, c = t & 63;

    // z1[b][c] = z1acc + sum_f z[b,f] * hb[f*64+c]
    float a = z1acc[t];
    #pragma unroll
    for (int i = 0; i < 3; ++i) {
        const float cv = sc[b * 3 + i];
        #pragma unroll 8
        for (int q = 0; q < 40; ++q)
            a += cv * sfreq[q] * hb[(i * 40 + q) * 64 + c];
    }
    sz[b][c] = a;  // no activation on modulated layer 0
    __syncthreads();

    float a1 = b1[c];
    #pragma unroll 8
    for (int cc = 0; cc < 64; ++cc) a1 += sz[b][cc] * w1[cc * 64 + c];
    s2[b][c] = fmaxf(a1, 0.f);
    __syncthreads();

    float a2 = b2[c];
    #pragma unroll 8
    for (int cc = 0; cc < 64; ++cc) a2 += s2[b][cc] * w2[cc * 64 + c];
    sz[b][c] = fmaxf(a2, 0.f);
    __syncthreads();

    if (t < 24) {
        const int bb = t / 3, i = t - bb * 3;
        float o = bo[i];
        #pragma unroll 8
        for (int cc = 0; cc < 64; ++cc) o += sz[bb][cc] * wo[cc * 3 + i];
        out[t] = o;
    }
}

// ---------------------------------------------------------------------------
extern "C" void kernel_launch(void* const* d_in, const int* in_sizes, int n_in,
                              void* d_out, int out_size, void* d_ws, size_t ws_size,
                              hipStream_t stream)
{
    const float* coord = (const float*)d_in[0];
    const float* feat0 = (const float*)d_in[1];
    const float* cw1 = (const float*)d_in[2];
    const float* cb1 = (const float*)d_in[3];
    const float* cw2 = (const float*)d_in[4];
    const float* cb2 = (const float*)d_in[5];
    const float* cw3 = (const float*)d_in[6];
    const float* cb3 = (const float*)d_in[7];
    const float* hw  = (const float*)d_in[8];
    const float* hb  = (const float*)d_in[9];
    const float* w1  = (const float*)d_in[10];
    const float* b1  = (const float*)d_in[11];
    const float* w2  = (const float*)d_in[12];
    const float* b2  = (const float*)d_in[13];
    const float* wo  = (const float*)d_in[14];
    const float* bo  = (const float*)d_in[15];
    float* out = (float*)d_out;

    float* fvecT = (float*)d_ws;              // 30720 * 8 floats = 983 KB
    float* z1acc = fvecT + (size_t)KTOT * 8;  // 512 floats

    hipMemsetAsync(z1acc, 0, 512 * sizeof(float), stream);
    k1_conv<<<dim3(8, 8, 8), 256, 0, stream>>>(feat0, cw1, cb1, cw2, cb2,
                                               cw3, cb3, fvecT);
    k2_stream<<<dim3(15, KSPLIT), 128, 0, stream>>>(hw, fvecT, coord, z1acc);
    k3_tail<<<1, 512, 0, stream>>>(z1acc, coord, hb, w1, b1, w2, b2, wo, bo, out);
}

// Round 2
// 306.336 us; speedup vs baseline: 1.6656x; 1.6656x over previous
//
#include <hip/hip_runtime.h>
#include <hip/hip_bf16.h>

#define DHW (16 * 16 * 30)   // 7680 voxels per channel
#define NWCOL 7680           // hw columns = 120 f * 64 c
#define KTOT 30720           // hw rows
#define KSPLIT 240
#define KCH (KTOT / KSPLIT)  // 128
#define NBLK (15 * KSPLIT)   // 3600 K2 blocks
// ln(1024)/39
#define LN1024_OVER_39 0.17773004629742187f

// ---------------------------------------------------------------------------
// K1: conv chain at strided voxels only. One block per (b, zi, yi); 15 w's.
// Writes fvecT[k][b], k = ((ch*8+zi)*8+yi)*15 + w   (torch flatten order)
// ---------------------------------------------------------------------------
__global__ __launch_bounds__(256) void k1_conv(
    const float* __restrict__ feat0,
    const float* __restrict__ cw1, const float* __restrict__ cb1,
    const float* __restrict__ cw2, const float* __restrict__ cb2,
    const float* __restrict__ cw3, const float* __restrict__ cb3,
    float* __restrict__ fvecT)
{
    const int yi = blockIdx.x;   // 0..7
    const int zi = blockIdx.y;   // 0..7
    const int b  = blockIdx.z;   // 0..7
    const int t  = threadIdx.x;  // 0..255

    __shared__ float sIn[256][16];
    __shared__ float sH1[128][16];
    __shared__ float sH2[64][16];

    // ---- load input voxels: feat0[b, c, 2zi, 2yi, 2w], w = 0..14 ----
    {
        const int w  = t & 15;
        const int cg = t >> 4;  // 0..15
        const float* base = feat0 + (size_t)b * 256 * DHW
                            + (2 * zi) * (16 * 30) + (2 * yi) * 30 + 2 * w;
        for (int c0 = 0; c0 < 256; c0 += 16) {
            const int c = c0 + cg;
            sIn[c][w] = (w < 15) ? base[(size_t)c * DHW] : 0.f;
        }
    }
    __syncthreads();

    // ---- conv1: 256 -> 128, relu.  thread: o = t&127, half = t>>7 ----
    {
        const int o = t & 127, half = t >> 7;
        const int w0 = half * 8;
        float acc[8];
        #pragma unroll
        for (int i = 0; i < 8; ++i) acc[i] = cb1[o];
        for (int c = 0; c < 256; ++c) {
            const float wv = cw1[c * 128 + o];
            #pragma unroll
            for (int i = 0; i < 8; ++i) acc[i] += sIn[c][w0 + i] * wv;
        }
        #pragma unroll
        for (int i = 0; i < 8; ++i) sH1[o][w0 + i] = fmaxf(acc[i], 0.f);
    }
    __syncthreads();

    // ---- conv2: 128 -> 64, relu.  thread: o = t&63, q = t>>6 (w quad) ----
    {
        const int o = t & 63, q = t >> 6;
        const int w0 = q * 4;
        float acc[4];
        #pragma unroll
        for (int i = 0; i < 4; ++i) acc[i] = cb2[o];
        for (int c = 0; c < 128; ++c) {
            const float wv = cw2[c * 64 + o];
            #pragma unroll
            for (int i = 0; i < 4; ++i) acc[i] += sH1[c][w0 + i] * wv;
        }
        #pragma unroll
        for (int i = 0; i < 4; ++i) sH2[o][w0 + i] = fmaxf(acc[i], 0.f);
    }
    __syncthreads();

    // ---- conv3: 64 -> 32, relu, scatter to fvecT.  o = t&31, q = t>>5 ----
    {
        const int o = t & 31, q = t >> 5;  // q = 0..7
        const int w0 = q * 2;
        float acc[2];
        #pragma unroll
        for (int i = 0; i < 2; ++i) acc[i] = cb3[o];
        for (int c = 0; c < 64; ++c) {
            const float wv = cw3[c * 32 + o];
            #pragma unroll
            for (int i = 0; i < 2; ++i) acc[i] += sH2[c][w0 + i] * wv;
        }
        #pragma unroll
        for (int i = 0; i < 2; ++i) {
            const int w = w0 + i;
            if (w < 15) {
                const int k = ((o * 8 + zi) * 8 + yi) * 15 + w;
                fvecT[(size_t)k * 8 + b] = fmaxf(acc[i], 0.f);
            }
        }
    }
}

// ---------------------------------------------------------------------------
// K2: stream hw once; per lane: 4 consecutive columns (one f, four c's),
// acc[b][e] over a k-chunk; fold z[b,f]; write per-block partial (no atomics).
// grid = (15 column groups of 512 cols, KSPLIT k-chunks), 128 threads.
// ---------------------------------------------------------------------------
__global__ __launch_bounds__(128) void k2_stream(
    const float* __restrict__ hw,
    const float* __restrict__ fvecT,
    const float* __restrict__ coord,
    float* __restrict__ partial)
{
    __shared__ float zpart[512];
    __shared__ float sF[KCH * 8];  // this k-chunk's fvec, all 8 batches (4 KB)
    const int t = threadIdx.x;
    const int kbase = blockIdx.y * KCH;

    #pragma unroll
    for (int r = 0; r < 4; ++r) zpart[t * 4 + r] = 0.f;
    #pragma unroll
    for (int i = 0; i < 8; ++i)
        sF[t + 128 * i] = fvecT[(size_t)kbase * 8 + t + 128 * i];
    __syncthreads();

    const int lane = t & 63;
    const int jw = blockIdx.x * 512 + (t >> 6) * 256;  // wave's 256-col strip
    const int j0 = jw + 4 * lane;                      // this lane's 4 cols

    float acc[8][4] = {};
    const float* hp = hw + (size_t)kbase * NWCOL + j0;

    #pragma unroll 4
    for (int kk = 0; kk < KCH; ++kk) {
        const float4 h = *(const float4*)hp;
        hp += NWCOL;
        const float4 f0 = *(const float4*)&sF[kk * 8];      // broadcast
        const float4 f1 = *(const float4*)&sF[kk * 8 + 4];  // broadcast
        const float fv[8] = {f0.x, f0.y, f0.z, f0.w, f1.x, f1.y, f1.z, f1.w};
        #pragma unroll
        for (int b = 0; b < 8; ++b) {
            acc[b][0] += fv[b] * h.x;
            acc[b][1] += fv[b] * h.y;
            acc[b][2] += fv[b] * h.z;
            acc[b][3] += fv[b] * h.w;
        }
    }

    // fold z[b, f] for this lane's f; accumulate into LDS z1 partial
    const int f = j0 >> 6;           // 0..119, constant over the 4 cols
    const int i3 = f / 40;           // coord dim
    const int q = f - i3 * 40;       // freq index
    const float freqv = __expf((float)q * LN1024_OVER_39);
    const int cb = 4 * (lane & 15);  // column (mod 64) of element e=0

    #pragma unroll
    for (int b = 0; b < 8; ++b) {
        const float zv = coord[b * 3 + i3] * freqv;
        #pragma unroll
        for (int e = 0; e < 4; ++e)
            atomicAdd(&zpart[b * 64 + cb + e], zv * acc[b][e]);
    }
    __syncthreads();

    // coalesced partial write: partial[bid][512]
    const int bid = blockIdx.x + 15 * blockIdx.y;
    float4* pp = (float4*)(partial + (size_t)bid * 512);
    pp[t] = *(const float4*)&zpart[t * 4];
}

// ---------------------------------------------------------------------------
// K2b: reduce partial[3600][512] -> z1[512]. 64 blocks x 256 threads.
// ---------------------------------------------------------------------------
__global__ __launch_bounds__(256) void k2b_reduce(
    const float* __restrict__ partial, float* __restrict__ z1)
{
    __shared__ float s[256];
    const int t = threadIdx.x;
    const int o = blockIdx.x * 8 + (t & 7);  // output element
    float sum = 0.f;
    for (int blk = t >> 3; blk < NBLK; blk += 32)
        sum += partial[(size_t)blk * 512 + o];
    s[t] = sum;
    __syncthreads();
    if (t < 8) {
        float tot = 0.f;
        #pragma unroll
        for (int i = 0; i < 32; ++i) tot += s[t + 8 * i];
        z1[blockIdx.x * 8 + t] = tot;
    }
}

// ---------------------------------------------------------------------------
// K3: hb-bias term + 3-layer MLP tail. One block, 512 threads = (b=8, c=64).
// ---------------------------------------------------------------------------
__global__ __launch_bounds__(512) void k3_tail(
    const float* __restrict__ z1acc, const float* __restrict__ coord,
    const float* __restrict__ hb,
    const float* __restrict__ w1, const float* __restrict__ b1,
    const float* __restrict__ w2, const float* __restrict__ b2,
    const float* __restrict__ wo, const float* __restrict__ bo,
    float* __restrict__ out)
{
    __shared__ float sz[8][64];
    __shared__ float s2[8][64];
    __shared__ float sfreq[40];
    __shared__ float sc[24];
    const int t = threadIdx.x;
    if (t < 40) sfreq[t] = __expf((float)t * LN1024_OVER_39);
    if (t < 24) sc[t] = coord[t];
    __syncthreads();

    const int b = t >> 6, c = t & 63;

    // z1[b][c] = z1acc + sum_f z[b,f] * hb[f*64+c]
    float a = z1acc[t];
    #pragma unroll
    for (int i = 0; i < 3; ++i) {
        const float cv = sc[b * 3 + i];
        #pragma unroll 8
        for (int q = 0; q < 40; ++q)
            a += cv * sfreq[q] * hb[(i * 40 + q) * 64 + c];
    }
    sz[b][c] = a;  // no activation on modulated layer 0
    __syncthreads();

    float a1 = b1[c];
    #pragma unroll 8
    for (int cc = 0; cc < 64; ++cc) a1 += sz[b][cc] * w1[cc * 64 + c];
    s2[b][c] = fmaxf(a1, 0.f);
    __syncthreads();

    float a2 = b2[c];
    #pragma unroll 8
    for (int cc = 0; cc < 64; ++cc) a2 += s2[b][cc] * w2[cc * 64 + c];
    sz[b][c] = fmaxf(a2, 0.f);
    __syncthreads();

    if (t < 24) {
        const int bb = t / 3, i = t - bb * 3;
        float o = bo[i];
        #pragma unroll 8
        for (int cc = 0; cc < 64; ++cc) o += sz[bb][cc] * wo[cc * 3 + i];
        out[t] = o;
    }
}

// ---------------------------------------------------------------------------
extern "C" void kernel_launch(void* const* d_in, const int* in_sizes, int n_in,
                              void* d_out, int out_size, void* d_ws, size_t ws_size,
                              hipStream_t stream)
{
    const float* coord = (const float*)d_in[0];
    const float* feat0 = (const float*)d_in[1];
    const float* cw1 = (const float*)d_in[2];
    const float* cb1 = (const float*)d_in[3];
    const float* cw2 = (const float*)d_in[4];
    const float* cb2 = (const float*)d_in[5];
    const float* cw3 = (const float*)d_in[6];
    const float* cb3 = (const float*)d_in[7];
    const float* hw  = (const float*)d_in[8];
    const float* hb  = (const float*)d_in[9];
    const float* w1  = (const float*)d_in[10];
    const float* b1  = (const float*)d_in[11];
    const float* w2  = (const float*)d_in[12];
    const float* b2  = (const float*)d_in[13];
    const float* wo  = (const float*)d_in[14];
    const float* bo  = (const float*)d_in[15];
    float* out = (float*)d_out;

    float* fvecT   = (float*)d_ws;                  // 30720*8 floats = 983 KB
    float* partial = fvecT + (size_t)KTOT * 8;      // 3600*512 floats = 7.37 MB
    float* z1      = partial + (size_t)NBLK * 512;  // 512 floats

    k1_conv<<<dim3(8, 8, 8), 256, 0, stream>>>(feat0, cw1, cb1, cw2, cb2,
                                               cw3, cb3, fvecT);
    k2_stream<<<dim3(15, KSPLIT), 128, 0, stream>>>(hw, fvecT, coord, partial);
    k2b_reduce<<<64, 256, 0, stream>>>(partial, z1);
    k3_tail<<<1, 512, 0, stream>>>(z1, coord, hb, w1, b1, w2, b2, wo, bo, out);
}